// Round 5
// baseline (233.149 us; speedup 1.0000x reference)
//
#include <hip/hip_runtime.h>
#include <math.h>

#define BS 16
#define C 64
#define H 128
#define W 128
#define HW (H*W)
#define NC 80
#define TOPK 128
#define KALL (TOPK+NC)
#define TAU 0.07f
#define EPSN 1e-12f
#define OUT_N 20971521          // 1 + BS*NC*HW
#define NCHW (NC*HW)            // 1310720
#define LOSSBLK (BS*NC)         // 1280 loss blocks
#define WBLK 5120               // writer blocks (256 thr, 4 float4 each)

// ---------------- find hm==1.0 peak per (b,n); -1 if absent ----------------
__global__ __launch_bounds__(1024) void k_peak(const float* __restrict__ hm,
                                               int* __restrict__ peak_pos) {
    __shared__ int wmax[16];
    int bn = blockIdx.x, t = threadIdx.x;
    int lane = t & 63, wid = t >> 6;
    const float4* p = (const float4*)(hm + (size_t)bn * HW);
    int found = -1;
    #pragma unroll
    for (int j = 0; j < 4; ++j) {
        int gi = j * 1024 + t;
        float4 v = p[gi];
        int base = gi * 4;
        if (v.x == 1.0f) found = base;
        if (v.y == 1.0f) found = base + 1;
        if (v.z == 1.0f) found = base + 2;
        if (v.w == 1.0f) found = base + 3;
    }
    #pragma unroll
    for (int off = 1; off < 64; off <<= 1) found = max(found, __shfl_xor(found, off));
    if (lane == 0) wmax[wid] = found;
    __syncthreads();
    if (t == 0) {
        int m = wmax[0];
        #pragma unroll
        for (int i = 1; i < 16; ++i) m = max(m, wmax[i]);
        peak_pos[bn] = m;
    }
}

// ---------------- per-pixel masked max/argmax over classes (4 px/thread) ----------------
__global__ void k_max(const float* __restrict__ score, const int* __restrict__ peak_pos,
                      float* __restrict__ maxv, int* __restrict__ clsidx) {
    __shared__ int pk[NC];
    int b = blockIdx.y;
    int g = blockIdx.x * blockDim.x + threadIdx.x;   // float4 group 0..4095
    if (threadIdx.x < NC) pk[threadIdx.x] = peak_pos[b * NC + threadIdx.x];
    __syncthreads();
    const float4* sb = (const float4*)(score + (size_t)b * NC * HW);
    int p0 = g * 4;
    int pp0 = pk[0];
    float m0 = (pp0 >= 0) ? 1.0f : 0.0f;
    float4 v0 = sb[g];
    float bx = v0.x * m0, by = v0.y * m0, bz = v0.z * m0, bw = v0.w * m0;
    int ix = 0, iy = 0, iz = 0, iw = 0;
    bool pe0 = (pp0 == p0), pe1 = (pp0 == p0 + 1), pe2 = (pp0 == p0 + 2), pe3 = (pp0 == p0 + 3);
    #pragma unroll 8
    for (int n = 1; n < NC; ++n) {
        int pp = pk[n];
        float m = (pp >= 0) ? 1.0f : 0.0f;
        float4 v = sb[(size_t)n * (HW / 4) + g];
        float vx = v.x * m, vy = v.y * m, vz = v.z * m, vw = v.w * m;
        if (vx > bx) { bx = vx; ix = n; }
        if (vy > by) { by = vy; iy = n; }
        if (vz > bz) { bz = vz; iz = n; }
        if (vw > bw) { bw = vw; iw = n; }
        pe0 |= (pp == p0); pe1 |= (pp == p0 + 1); pe2 |= (pp == p0 + 2); pe3 |= (pp == p0 + 3);
    }
    if (pe0) { bx = 0.0f; ix = 0; }
    if (pe1) { by = 0.0f; iy = 0; }
    if (pe2) { bz = 0.0f; iz = 0; }
    if (pe3) { bw = 0.0f; iw = 0; }
    ((float4*)maxv)[(size_t)b * (HW / 4) + g] = make_float4(bx, by, bz, bw);
    ((int4*)clsidx)[(size_t)b * (HW / 4) + g] = make_int4(ix, iy, iz, iw);
}

// ---------------- radix-select top-128 + build map + gather/normalize ----------------
__global__ __launch_bounds__(1024) void k_topk_gather(const float* __restrict__ maxv,
                                                      const int* __restrict__ clsidx,
                                                      const float* __restrict__ feat,
                                                      const int* __restrict__ peak_pos,
                                                      float* __restrict__ topkv,
                                                      int* __restrict__ topkc,
                                                      unsigned char* __restrict__ map,
                                                      float* __restrict__ k_all,
                                                      float* __restrict__ qv,
                                                      int* __restrict__ counter) {
    __shared__ unsigned int hist[2048];
    __shared__ unsigned int wtot[16];
    __shared__ unsigned int woff[16];
    __shared__ unsigned int s_pref;
    __shared__ int s_rank;
    __shared__ unsigned int s_bin;
    __shared__ unsigned int s_above;
    __shared__ int s_ki[TOPK];
    __shared__ int s_pk[NC];

    int b = blockIdx.x, t = threadIdx.x;
    int lane = t & 63, wid = t >> 6;

    if (b == 0 && t == 0) *counter = 0;                // reset for k_write_loss
    // zero this batch's map (16 KB)
    {
        unsigned int* mz = (unsigned int*)(map + (size_t)b * HW);
        #pragma unroll
        for (int j = 0; j < 4; ++j) mz[j * 1024 + t] = 0u;
    }
    if (t < NC) s_pk[t] = peak_pos[b * NC + t];

    unsigned int key[16];
    const float4* mv4 = (const float4*)(maxv + (size_t)b * HW);
    #pragma unroll
    for (int j4 = 0; j4 < 4; ++j4) {
        float4 v = mv4[t * 4 + j4];
        key[j4 * 4 + 0] = __float_as_uint(v.x);
        key[j4 * 4 + 1] = __float_as_uint(v.y);
        key[j4 * 4 + 2] = __float_as_uint(v.z);
        key[j4 * 4 + 3] = __float_as_uint(v.w);
    }

    if (t == 0) { s_pref = 0u; s_rank = TOPK; }

    const int shifts[3] = {21, 10, 0};
    const int widths[3] = {11, 11, 10};

    for (int rnd = 0; rnd < 3; ++rnd) {
        int sh = shifts[rnd], w = widths[rnd];
        unsigned mask = (1u << w) - 1u;
        hist[t] = 0u; hist[t + 1024] = 0u;
        __syncthreads();
        unsigned pref = s_pref;
        int hiShift = sh + w;
        #pragma unroll
        for (int j = 0; j < 16; ++j) {
            unsigned k = key[j];
            bool ok = (rnd == 0) || ((k >> hiShift) == pref);
            if (ok) atomicAdd(&hist[(k >> sh) & mask], 1u);
        }
        __syncthreads();
        unsigned p = hist[2 * t] + hist[2 * t + 1];
        unsigned s = p;
        #pragma unroll
        for (int off = 1; off < 64; off <<= 1) {
            unsigned o = __shfl_down(s, off);
            if (lane + off < 64) s += o;
        }
        if (lane == 0) wtot[wid] = s;
        __syncthreads();
        if (wid == 0) {
            unsigned vv = (lane < 16) ? wtot[lane] : 0u;
            unsigned ss = vv;
            #pragma unroll
            for (int off = 1; off < 64; off <<= 1) {
                unsigned o = __shfl_down(ss, off);
                if (lane + off < 64) ss += o;
            }
            if (lane < 16) woff[lane] = ss - vv;
        }
        __syncthreads();
        unsigned S_t = s + woff[wid];
        unsigned S_next = S_t - p;
        int r = s_rank;
        if ((int)S_t >= r && (int)S_next < r) {
            unsigned hi = hist[2 * t + 1];
            if ((int)(S_next + hi) >= r) { s_bin = 2u * t + 1u; s_above = S_next; }
            else                         { s_bin = 2u * t;      s_above = S_next + hi; }
        }
        __syncthreads();
        if (t == 0) {
            s_pref = (s_pref << w) | s_bin;
            s_rank = s_rank - (int)s_above;
        }
        __syncthreads();
    }
    unsigned K = s_pref;
    int need_eq = s_rank;
    int cnt_gt = TOPK - need_eq;

    int cg = 0, ce = 0;
    #pragma unroll
    for (int j = 0; j < 16; ++j) { cg += (key[j] > K); ce += (key[j] == K); }
    unsigned v = ((unsigned)cg << 16) | (unsigned)ce;
    unsigned sc = v;
    #pragma unroll
    for (int off = 1; off < 64; off <<= 1) {
        unsigned o = __shfl_up(sc, off);
        if (lane >= off) sc += o;
    }
    if (lane == 63) wtot[wid] = sc;
    __syncthreads();
    if (wid == 0) {
        unsigned vv = (lane < 16) ? wtot[lane] : 0u;
        unsigned ss = vv;
        #pragma unroll
        for (int off = 1; off < 64; off <<= 1) {
            unsigned o = __shfl_up(ss, off);
            if (lane >= off) ss += o;
        }
        if (lane < 16) woff[lane] = ss - vv;
    }
    __syncthreads();
    unsigned ex = (sc - v) + woff[wid];
    int pg = (int)(ex >> 16);
    int pe = (int)(ex & 0xffffu);
    int lg = 0, le = 0;
    #pragma unroll
    for (int j = 0; j < 16; ++j) {
        unsigned k = key[j];
        int slot = -1;
        if (k > K) { slot = pg + lg; ++lg; }
        else if (k == K) { int er = pe + le; ++le; if (er < need_eq) slot = cnt_gt + er; }
        if (slot >= 0) {
            int idx = t * 16 + j;
            int cls = clsidx[(size_t)b * HW + idx];
            topkv[b * TOPK + slot] = __uint_as_float(k);
            topkc[b * TOPK + slot] = cls;
            s_ki[slot] = idx;
            if (__uint_as_float(k) > 0.0f)
                map[(size_t)b * HW + idx] = (unsigned char)(cls + 1);  // byte store, race-free
        }
    }
    __syncthreads();

    // ---- gather + normalize 208 positions (16 waves x 13 passes) ----
    for (int p13 = 0; p13 < 13; ++p13) {
        int pi = p13 * 16 + wid;          // 0..207
        int pos = (pi < TOPK) ? s_ki[pi] : s_pk[pi - TOPK];
        int c = lane;
        if (pos < 0) {                    // absent class (pi>=TOPK only)
            k_all[((size_t)b * KALL + pi) * C + c] = 0.0f;
            qv[((size_t)b * NC + (pi - TOPK)) * C + c] = 0.0f;
            continue;
        }
        float fv = feat[((size_t)b * C + c) * HW + pos];
        float ss = fv * fv;
        #pragma unroll
        for (int off = 1; off < 64; off <<= 1) ss += __shfl_xor(ss, off);
        float qc = fv / fmaxf(sqrtf(ss), EPSN);
        if (pi < TOPK) {
            k_all[((size_t)b * KALL + pi) * C + c] = qc;
        } else {
            qv[((size_t)b * NC + (pi - TOPK)) * C + c] = qc;
            float qq = qc * qc;
            #pragma unroll
            for (int off = 1; off < 64; off <<= 1) qq += __shfl_xor(qq, off);
            k_all[((size_t)b * KALL + pi) * C + c] = qc / fmaxf(sqrtf(qq), EPSN);
        }
    }
}

// ---------------- fused: loss (blocks 0..1279, + last-block final) and
//                  full pseudo_hm write (blocks 1280..6399) ----------------
__global__ __launch_bounds__(256) void k_write_loss(const float* __restrict__ k_all,
                                                    const float* __restrict__ qv,
                                                    const int* __restrict__ peak_pos,
                                                    const float* __restrict__ topkv,
                                                    const int* __restrict__ topkc,
                                                    const unsigned char* __restrict__ map,
                                                    float* __restrict__ loss_bn,
                                                    int* __restrict__ counter,
                                                    float* __restrict__ out) {
    int t = threadIdx.x;
    if (blockIdx.x >= LOSSBLK) {
        // ---------- writer: 5120 blocks x 256 thr x 4 float4 ----------
        int zb = blockIdx.x - LOSSBLK;
        int idx = zb * 256 + t;                       // [0, 1310720)
        float4* o4 = (float4*)out;
        #pragma unroll
        for (int j = 0; j < 4; ++j) {
            int g = idx + j * (WBLK * 256);           // [0, 5242880)
            float r[4];
            #pragma unroll
            for (int k = 0; k < 4; ++k) {
                int e = 4 * g + k;
                float val = 0.0f;
                if (e > 0) {
                    int linear = e - 1;
                    int bb = linear / NCHW;
                    int rr = linear - bb * NCHW;
                    int n = rr >> 14;
                    int pos = rr & (HW - 1);
                    unsigned char mp = map[((size_t)bb << 14) + pos];
                    val = (mp == (unsigned char)(n + 1)) ? 0.9f : 0.0f;
                }
                r[k] = val;
            }
            if (g == 0) {                             // skip out[0] (loss slot)
                out[1] = r[1]; out[2] = r[2]; out[3] = r[3];
            } else {
                o4[g] = make_float4(r[0], r[1], r[2], r[3]);
            }
        }
        if (zb == 0 && t == 0) {                      // tail element e = OUT_N-1
            int linear = OUT_N - 2;
            int bb = linear / NCHW;
            int rr = linear - bb * NCHW;
            int n = rr >> 14;
            int pos = rr & (HW - 1);
            unsigned char mp = map[((size_t)bb << 14) + pos];
            out[OUT_N - 1] = (mp == (unsigned char)(n + 1)) ? 0.9f : 0.0f;
        }
        return;
    }
    // ---------- loss block for (b,n) ----------
    __shared__ float qs[C];
    __shared__ float r1[256];
    __shared__ float r2[256];
    __shared__ float s_simsum, s_num;
    __shared__ int s_last;
    int bn = blockIdx.x;
    int b = bn / NC, n = bn % NC;
    bool present = (peak_pos[bn] >= 0);
    float sim = 0.0f, kam = 0.0f, km = 0.0f;
    if (present) {
        if (t < C) qs[t] = qv[(size_t)bn * C + t];
        __syncthreads();
        if (t < KALL) {
            const float* kr = k_all + ((size_t)b * KALL + t) * C;
            float dot = 0.0f;
            for (int c2 = 0; c2 < C; ++c2) dot += qs[c2] * kr[c2];
            sim = expf(dot / TAU);
            if (t < TOPK) {
                float posm = (topkv[b * TOPK + t] > 0.0f) ? 1.0f : 0.0f;
                kam = posm;
                km = (topkc[b * TOPK + t] == n) ? posm : 0.0f;
            } else {
                int j = t - TOPK;
                kam = (peak_pos[b * NC + j] >= 0) ? 1.0f : 0.0f;
                km = (j == n) ? 1.0f : 0.0f;
            }
        }
        r1[t] = sim * kam;
        r2[t] = km;
        __syncthreads();
        for (int s = 128; s > 0; s >>= 1) {
            if (t < s) { r1[t] += r1[t + s]; r2[t] += r2[t + s]; }
            __syncthreads();
        }
        if (t == 0) {
            float ss = r1[0];
            s_simsum = (ss == 0.0f) ? 1.0f : ss;
            s_num = (r2[0] == 0.0f) ? 1.0f : r2[0];
        }
        __syncthreads();
        r1[t] = (km > 0.0f) ? logf(sim / s_simsum) : 0.0f;
        __syncthreads();
        for (int s = 128; s > 0; s >>= 1) {
            if (t < s) r1[t] += r1[t + s];
            __syncthreads();
        }
        if (t == 0) loss_bn[bn] = r1[0] / s_num;
    } else {
        if (t == 0) loss_bn[bn] = 0.0f;
    }
    // last-finishing loss block does the final reduction
    __threadfence();
    __syncthreads();
    if (t == 0) s_last = (atomicAdd(counter, 1) == LOSSBLK - 1) ? 1 : 0;
    __syncthreads();
    if (s_last) {
        __threadfence();
        float s = 0.0f, cnt = 0.0f;
        for (int i = t; i < BS * NC; i += 256) {
            s += loss_bn[i];
            cnt += (peak_pos[i] >= 0) ? 1.0f : 0.0f;
        }
        r1[t] = s; r2[t] = cnt;
        __syncthreads();
        for (int st = 128; st > 0; st >>= 1) {
            if (t < st) { r1[t] += r1[t + st]; r2[t] += r2[t + st]; }
            __syncthreads();
        }
        if (t == 0) out[0] = -(r1[0] / r2[0]);
    }
}

extern "C" void kernel_launch(void* const* d_in, const int* in_sizes, int n_in,
                              void* d_out, int out_size, void* d_ws, size_t ws_size,
                              hipStream_t stream) {
    const float* feat  = (const float*)d_in[0];
    const float* score = (const float*)d_in[1];
    const float* hm    = (const float*)d_in[2];
    float* out = (float*)d_out;

    char* ws = (char*)d_ws;
    size_t off = 0;
    auto alloc = [&](size_t bytes) -> void* {
        void* p = ws + off;
        off += (bytes + 255) & ~(size_t)255;
        return p;
    };
    int*   peak_pos = (int*)  alloc((size_t)BS * NC * 4);
    float* maxv     = (float*)alloc((size_t)BS * HW * 4);
    int*   clsidx   = (int*)  alloc((size_t)BS * HW * 4);
    float* topkv    = (float*)alloc((size_t)BS * TOPK * 4);
    int*   topkc    = (int*)  alloc((size_t)BS * TOPK * 4);
    float* k_all    = (float*)alloc((size_t)BS * KALL * C * 4);
    float* qv       = (float*)alloc((size_t)BS * NC * C * 4);
    float* loss_bn  = (float*)alloc((size_t)BS * NC * 4);
    unsigned char* map = (unsigned char*)alloc((size_t)BS * HW);
    int*   counter  = (int*)  alloc(256);

    k_peak<<<BS * NC, 1024, 0, stream>>>(hm, peak_pos);
    dim3 gmax(HW / 4 / 256, BS);
    k_max<<<gmax, 256, 0, stream>>>(score, peak_pos, maxv, clsidx);
    k_topk_gather<<<BS, 1024, 0, stream>>>(maxv, clsidx, feat, peak_pos,
                                           topkv, topkc, map, k_all, qv, counter);
    k_write_loss<<<LOSSBLK + WBLK, 256, 0, stream>>>(k_all, qv, peak_pos, topkv, topkc,
                                                     map, loss_bn, counter, out);
}

// Round 6
// 111.241 us; speedup vs baseline: 2.0959x; 2.0959x over previous
//
#include <hip/hip_runtime.h>
#include <math.h>

#define BS 16
#define C 64
#define H 128
#define W 128
#define HW (H*W)
#define NC 80
#define TOPK 128
#define KALL (TOPK+NC)
#define TAU 0.07f
#define EPSN 1e-12f
#define OUT_N 20971521          // 1 + BS*NC*HW
#define NCHW (NC*HW)            // 1310720
#define WBLK 2560               // writer blocks: 256 thr x 32 dword each = 32KB/block

// ---------------- find hm==1.0 peak per (b,n); -1 if absent ----------------
__global__ __launch_bounds__(1024) void k_peak(const float* __restrict__ hm,
                                               int* __restrict__ peak_pos) {
    __shared__ int wmax[16];
    int bn = blockIdx.x, t = threadIdx.x;
    int lane = t & 63, wid = t >> 6;
    const float4* p = (const float4*)(hm + (size_t)bn * HW);
    int found = -1;
    #pragma unroll
    for (int j = 0; j < 4; ++j) {
        int gi = j * 1024 + t;
        float4 v = p[gi];
        int base = gi * 4;
        if (v.x == 1.0f) found = base;
        if (v.y == 1.0f) found = base + 1;
        if (v.z == 1.0f) found = base + 2;
        if (v.w == 1.0f) found = base + 3;
    }
    #pragma unroll
    for (int off = 1; off < 64; off <<= 1) found = max(found, __shfl_xor(found, off));
    if (lane == 0) wmax[wid] = found;
    __syncthreads();
    if (t == 0) {
        int m = wmax[0];
        #pragma unroll
        for (int i = 1; i < 16; ++i) m = max(m, wmax[i]);
        peak_pos[bn] = m;
    }
}

// ---------------- per-pixel masked max/argmax over classes (4 px/thread) ----------------
__global__ void k_max(const float* __restrict__ score, const int* __restrict__ peak_pos,
                      float* __restrict__ maxv, int* __restrict__ clsidx) {
    __shared__ int pk[NC];
    int b = blockIdx.y;
    int g = blockIdx.x * blockDim.x + threadIdx.x;   // float4 group 0..4095
    if (threadIdx.x < NC) pk[threadIdx.x] = peak_pos[b * NC + threadIdx.x];
    __syncthreads();
    const float4* sb = (const float4*)(score + (size_t)b * NC * HW);
    int p0 = g * 4;
    int pp0 = pk[0];
    float m0 = (pp0 >= 0) ? 1.0f : 0.0f;
    float4 v0 = sb[g];
    float bx = v0.x * m0, by = v0.y * m0, bz = v0.z * m0, bw = v0.w * m0;
    int ix = 0, iy = 0, iz = 0, iw = 0;
    bool pe0 = (pp0 == p0), pe1 = (pp0 == p0 + 1), pe2 = (pp0 == p0 + 2), pe3 = (pp0 == p0 + 3);
    #pragma unroll 8
    for (int n = 1; n < NC; ++n) {
        int pp = pk[n];
        float m = (pp >= 0) ? 1.0f : 0.0f;
        float4 v = sb[(size_t)n * (HW / 4) + g];
        float vx = v.x * m, vy = v.y * m, vz = v.z * m, vw = v.w * m;
        if (vx > bx) { bx = vx; ix = n; }
        if (vy > by) { by = vy; iy = n; }
        if (vz > bz) { bz = vz; iz = n; }
        if (vw > bw) { bw = vw; iw = n; }
        pe0 |= (pp == p0); pe1 |= (pp == p0 + 1); pe2 |= (pp == p0 + 2); pe3 |= (pp == p0 + 3);
    }
    if (pe0) { bx = 0.0f; ix = 0; }
    if (pe1) { by = 0.0f; iy = 0; }
    if (pe2) { bz = 0.0f; iz = 0; }
    if (pe3) { bw = 0.0f; iw = 0; }
    ((float4*)maxv)[(size_t)b * (HW / 4) + g] = make_float4(bx, by, bz, bw);
    ((int4*)clsidx)[(size_t)b * (HW / 4) + g] = make_int4(ix, iy, iz, iw);
}

// ---------------- radix-select top-128 + build map + gather/normalize ----------------
__global__ __launch_bounds__(1024) void k_topk_gather(const float* __restrict__ maxv,
                                                      const int* __restrict__ clsidx,
                                                      const float* __restrict__ feat,
                                                      const int* __restrict__ peak_pos,
                                                      float* __restrict__ topkv,
                                                      int* __restrict__ topkc,
                                                      unsigned char* __restrict__ map,
                                                      float* __restrict__ k_all,
                                                      float* __restrict__ qv) {
    __shared__ unsigned int hist[2048];
    __shared__ unsigned int wtot[16];
    __shared__ unsigned int woff[16];
    __shared__ unsigned int s_pref;
    __shared__ int s_rank;
    __shared__ unsigned int s_bin;
    __shared__ unsigned int s_above;
    __shared__ int s_ki[TOPK];
    __shared__ int s_pk[NC];

    int b = blockIdx.x, t = threadIdx.x;
    int lane = t & 63, wid = t >> 6;

    // zero this batch's map (16 KB)
    {
        unsigned int* mz = (unsigned int*)(map + (size_t)b * HW);
        #pragma unroll
        for (int j = 0; j < 4; ++j) mz[j * 1024 + t] = 0u;
    }
    if (t < NC) s_pk[t] = peak_pos[b * NC + t];

    unsigned int key[16];
    const float4* mv4 = (const float4*)(maxv + (size_t)b * HW);
    #pragma unroll
    for (int j4 = 0; j4 < 4; ++j4) {
        float4 v = mv4[t * 4 + j4];
        key[j4 * 4 + 0] = __float_as_uint(v.x);
        key[j4 * 4 + 1] = __float_as_uint(v.y);
        key[j4 * 4 + 2] = __float_as_uint(v.z);
        key[j4 * 4 + 3] = __float_as_uint(v.w);
    }

    if (t == 0) { s_pref = 0u; s_rank = TOPK; }

    const int shifts[3] = {21, 10, 0};
    const int widths[3] = {11, 11, 10};

    for (int rnd = 0; rnd < 3; ++rnd) {
        int sh = shifts[rnd], w = widths[rnd];
        unsigned mask = (1u << w) - 1u;
        hist[t] = 0u; hist[t + 1024] = 0u;
        __syncthreads();
        unsigned pref = s_pref;
        int hiShift = sh + w;
        #pragma unroll
        for (int j = 0; j < 16; ++j) {
            unsigned k = key[j];
            bool ok = (rnd == 0) || ((k >> hiShift) == pref);
            if (ok) atomicAdd(&hist[(k >> sh) & mask], 1u);
        }
        __syncthreads();
        unsigned p = hist[2 * t] + hist[2 * t + 1];
        unsigned s = p;
        #pragma unroll
        for (int off = 1; off < 64; off <<= 1) {
            unsigned o = __shfl_down(s, off);
            if (lane + off < 64) s += o;
        }
        if (lane == 0) wtot[wid] = s;
        __syncthreads();
        if (wid == 0) {
            unsigned vv = (lane < 16) ? wtot[lane] : 0u;
            unsigned ss = vv;
            #pragma unroll
            for (int off = 1; off < 64; off <<= 1) {
                unsigned o = __shfl_down(ss, off);
                if (lane + off < 64) ss += o;
            }
            if (lane < 16) woff[lane] = ss - vv;
        }
        __syncthreads();
        unsigned S_t = s + woff[wid];
        unsigned S_next = S_t - p;
        int r = s_rank;
        if ((int)S_t >= r && (int)S_next < r) {
            unsigned hi = hist[2 * t + 1];
            if ((int)(S_next + hi) >= r) { s_bin = 2u * t + 1u; s_above = S_next; }
            else                         { s_bin = 2u * t;      s_above = S_next + hi; }
        }
        __syncthreads();
        if (t == 0) {
            s_pref = (s_pref << w) | s_bin;
            s_rank = s_rank - (int)s_above;
        }
        __syncthreads();
    }
    unsigned K = s_pref;
    int need_eq = s_rank;
    int cnt_gt = TOPK - need_eq;

    int cg = 0, ce = 0;
    #pragma unroll
    for (int j = 0; j < 16; ++j) { cg += (key[j] > K); ce += (key[j] == K); }
    unsigned v = ((unsigned)cg << 16) | (unsigned)ce;
    unsigned sc = v;
    #pragma unroll
    for (int off = 1; off < 64; off <<= 1) {
        unsigned o = __shfl_up(sc, off);
        if (lane >= off) sc += o;
    }
    if (lane == 63) wtot[wid] = sc;
    __syncthreads();
    if (wid == 0) {
        unsigned vv = (lane < 16) ? wtot[lane] : 0u;
        unsigned ss = vv;
        #pragma unroll
        for (int off = 1; off < 64; off <<= 1) {
            unsigned o = __shfl_up(ss, off);
            if (lane >= off) ss += o;
        }
        if (lane < 16) woff[lane] = ss - vv;
    }
    __syncthreads();
    unsigned ex = (sc - v) + woff[wid];
    int pg = (int)(ex >> 16);
    int pe = (int)(ex & 0xffffu);
    int lg = 0, le = 0;
    #pragma unroll
    for (int j = 0; j < 16; ++j) {
        unsigned k = key[j];
        int slot = -1;
        if (k > K) { slot = pg + lg; ++lg; }
        else if (k == K) { int er = pe + le; ++le; if (er < need_eq) slot = cnt_gt + er; }
        if (slot >= 0) {
            int idx = t * 16 + j;
            int cls = clsidx[(size_t)b * HW + idx];
            topkv[b * TOPK + slot] = __uint_as_float(k);
            topkc[b * TOPK + slot] = cls;
            s_ki[slot] = idx;
            if (__uint_as_float(k) > 0.0f)
                map[(size_t)b * HW + idx] = (unsigned char)(cls + 1);  // byte store, race-free
        }
    }
    __syncthreads();

    // ---- gather + normalize 208 positions (16 waves x 13 passes) ----
    for (int p13 = 0; p13 < 13; ++p13) {
        int pi = p13 * 16 + wid;          // 0..207
        int pos = (pi < TOPK) ? s_ki[pi] : s_pk[pi - TOPK];
        int c = lane;
        if (pos < 0) {                    // absent class (pi>=TOPK only)
            k_all[((size_t)b * KALL + pi) * C + c] = 0.0f;
            qv[((size_t)b * NC + (pi - TOPK)) * C + c] = 0.0f;
            continue;
        }
        float fv = feat[((size_t)b * C + c) * HW + pos];
        float ss = fv * fv;
        #pragma unroll
        for (int off = 1; off < 64; off <<= 1) ss += __shfl_xor(ss, off);
        float qc = fv / fmaxf(sqrtf(ss), EPSN);
        if (pi < TOPK) {
            k_all[((size_t)b * KALL + pi) * C + c] = qc;
        } else {
            qv[((size_t)b * NC + (pi - TOPK)) * C + c] = qc;
            float qq = qc * qc;
            #pragma unroll
            for (int off = 1; off < 64; off <<= 1) qq += __shfl_xor(qq, off);
            k_all[((size_t)b * KALL + pi) * C + c] = qc / fmaxf(sqrtf(qq), EPSN);
        }
    }
}

// ---------------- contrastive loss per (b,n) — fence-free ----------------
__global__ __launch_bounds__(256) void k_loss(const float* __restrict__ k_all,
                                              const float* __restrict__ qv,
                                              const int* __restrict__ peak_pos,
                                              const float* __restrict__ topkv,
                                              const int* __restrict__ topkc,
                                              float* __restrict__ loss_bn) {
    __shared__ float qs[C];
    __shared__ float r1[256];
    __shared__ float r2[256];
    __shared__ float s_simsum, s_num;
    int bn = blockIdx.x;
    int b = bn / NC, n = bn % NC, t = threadIdx.x;
    if (peak_pos[bn] < 0) { if (t == 0) loss_bn[bn] = 0.0f; return; }
    if (t < C) qs[t] = qv[(size_t)bn * C + t];
    __syncthreads();
    float sim = 0.0f, kam = 0.0f, km = 0.0f;
    if (t < KALL) {
        const float* kr = k_all + ((size_t)b * KALL + t) * C;
        float dot = 0.0f;
        for (int c2 = 0; c2 < C; ++c2) dot += qs[c2] * kr[c2];
        sim = expf(dot / TAU);
        if (t < TOPK) {
            float posm = (topkv[b * TOPK + t] > 0.0f) ? 1.0f : 0.0f;
            kam = posm;
            km = (topkc[b * TOPK + t] == n) ? posm : 0.0f;
        } else {
            int j = t - TOPK;
            kam = (peak_pos[b * NC + j] >= 0) ? 1.0f : 0.0f;
            km = (j == n) ? 1.0f : 0.0f;
        }
    }
    r1[t] = sim * kam;
    r2[t] = km;
    __syncthreads();
    for (int s = 128; s > 0; s >>= 1) {
        if (t < s) { r1[t] += r1[t + s]; r2[t] += r2[t + s]; }
        __syncthreads();
    }
    if (t == 0) {
        float ss = r1[0];
        s_simsum = (ss == 0.0f) ? 1.0f : ss;
        s_num = (r2[0] == 0.0f) ? 1.0f : r2[0];
    }
    __syncthreads();
    r1[t] = (km > 0.0f) ? logf(sim / s_simsum) : 0.0f;
    __syncthreads();
    for (int s = 128; s > 0; s >>= 1) {
        if (t < s) r1[t] += r1[t + s];
        __syncthreads();
    }
    if (t == 0) loss_bn[bn] = r1[0] / s_num;
}

// ---------------- pure streaming writer (+ lone final-reduce block) ----------------
// out[1+linear] = (map[b][pos] == n+1) ? 0.9 : 0, fully coalesced, no fences.
__global__ __launch_bounds__(256) void k_write_final(const unsigned char* __restrict__ map,
                                                     const float* __restrict__ loss_bn,
                                                     const int* __restrict__ peak_pos,
                                                     float* __restrict__ out) {
    int t = threadIdx.x;
    if (blockIdx.x < WBLK) {
        int base = blockIdx.x * 8192 + t;            // pseudo element, k=0
        #pragma unroll
        for (int k = 0; k < 32; ++k) {
            int linear = base + k * 256;             // [0, 20971520)
            int hi = linear >> 14;                   // (b*NC + n)
            int bb = hi / NC;                        // magic-div by 80
            int n1 = hi - bb * NC + 1;               // n+1
            int pos = linear & (HW - 1);
            unsigned char mp = map[(bb << 14) + pos];
            float v = (mp == (unsigned char)n1) ? 0.9f : 0.0f;
            __builtin_nontemporal_store(v, &out[1 + linear]);
        }
        return;
    }
    // ---- final loss reduction (single block; loss_bn from previous kernel) ----
    __shared__ float r1[256];
    __shared__ float r2[256];
    float s = 0.0f, cnt = 0.0f;
    for (int i = t; i < BS * NC; i += 256) {
        s += loss_bn[i];
        cnt += (peak_pos[i] >= 0) ? 1.0f : 0.0f;
    }
    r1[t] = s; r2[t] = cnt;
    __syncthreads();
    for (int st = 128; st > 0; st >>= 1) {
        if (t < st) { r1[t] += r1[t + st]; r2[t] += r2[t + st]; }
        __syncthreads();
    }
    if (t == 0) out[0] = -(r1[0] / r2[0]);
}

extern "C" void kernel_launch(void* const* d_in, const int* in_sizes, int n_in,
                              void* d_out, int out_size, void* d_ws, size_t ws_size,
                              hipStream_t stream) {
    const float* feat  = (const float*)d_in[0];
    const float* score = (const float*)d_in[1];
    const float* hm    = (const float*)d_in[2];
    float* out = (float*)d_out;

    char* ws = (char*)d_ws;
    size_t off = 0;
    auto alloc = [&](size_t bytes) -> void* {
        void* p = ws + off;
        off += (bytes + 255) & ~(size_t)255;
        return p;
    };
    int*   peak_pos = (int*)  alloc((size_t)BS * NC * 4);
    float* maxv     = (float*)alloc((size_t)BS * HW * 4);
    int*   clsidx   = (int*)  alloc((size_t)BS * HW * 4);
    float* topkv    = (float*)alloc((size_t)BS * TOPK * 4);
    int*   topkc    = (int*)  alloc((size_t)BS * TOPK * 4);
    float* k_all    = (float*)alloc((size_t)BS * KALL * C * 4);
    float* qv       = (float*)alloc((size_t)BS * NC * C * 4);
    float* loss_bn  = (float*)alloc((size_t)BS * NC * 4);
    unsigned char* map = (unsigned char*)alloc((size_t)BS * HW);

    k_peak<<<BS * NC, 1024, 0, stream>>>(hm, peak_pos);
    dim3 gmax(HW / 4 / 256, BS);
    k_max<<<gmax, 256, 0, stream>>>(score, peak_pos, maxv, clsidx);
    k_topk_gather<<<BS, 1024, 0, stream>>>(maxv, clsidx, feat, peak_pos,
                                           topkv, topkc, map, k_all, qv);
    k_loss<<<BS * NC, 256, 0, stream>>>(k_all, qv, peak_pos, topkv, topkc, loss_bn);
    k_write_final<<<WBLK + 1, 256, 0, stream>>>(map, loss_bn, peak_pos, out);
}

// Round 7
// 101.823 us; speedup vs baseline: 2.2898x; 1.0925x over previous
//
#include <hip/hip_runtime.h>
#include <math.h>

#define BS 16
#define C 64
#define H 128
#define W 128
#define HW (H*W)
#define NC 80
#define TOPK 128
#define KALL (TOPK+NC)
#define TAU 0.07f
#define EPSN 1e-12f
#define OUT_N 20971521          // 1 + BS*NC*HW
#define NCHW (NC*HW)            // 1310720
#define WBLK 2560               // writer blocks: 256 thr x 32 dword each = 32KB/block

// ---------------- find hm==1.0 peak per (b,n); -1 if absent ----------------
__global__ __launch_bounds__(1024) void k_peak(const float* __restrict__ hm,
                                               int* __restrict__ peak_pos) {
    __shared__ int wmax[16];
    int bn = blockIdx.x, t = threadIdx.x;
    int lane = t & 63, wid = t >> 6;
    const float4* p = (const float4*)(hm + (size_t)bn * HW);
    int found = -1;
    #pragma unroll
    for (int j = 0; j < 4; ++j) {
        int gi = j * 1024 + t;
        float4 v = p[gi];
        int base = gi * 4;
        if (v.x == 1.0f) found = base;
        if (v.y == 1.0f) found = base + 1;
        if (v.z == 1.0f) found = base + 2;
        if (v.w == 1.0f) found = base + 3;
    }
    #pragma unroll
    for (int off = 1; off < 64; off <<= 1) found = max(found, __shfl_xor(found, off));
    if (lane == 0) wmax[wid] = found;
    __syncthreads();
    if (t == 0) {
        int m = wmax[0];
        #pragma unroll
        for (int i = 1; i < 16; ++i) m = max(m, wmax[i]);
        peak_pos[bn] = m;
    }
}

// ---------------- per-pixel masked max/argmax over classes (4 px/thread) ----------------
__global__ void k_max(const float* __restrict__ score, const int* __restrict__ peak_pos,
                      float* __restrict__ maxv, int* __restrict__ clsidx) {
    __shared__ int pk[NC];
    int b = blockIdx.y;
    int g = blockIdx.x * blockDim.x + threadIdx.x;   // float4 group 0..4095
    if (threadIdx.x < NC) pk[threadIdx.x] = peak_pos[b * NC + threadIdx.x];
    __syncthreads();
    const float4* sb = (const float4*)(score + (size_t)b * NC * HW);
    int p0 = g * 4;
    int pp0 = pk[0];
    float m0 = (pp0 >= 0) ? 1.0f : 0.0f;
    float4 v0 = sb[g];
    float bx = v0.x * m0, by = v0.y * m0, bz = v0.z * m0, bw = v0.w * m0;
    int ix = 0, iy = 0, iz = 0, iw = 0;
    bool pe0 = (pp0 == p0), pe1 = (pp0 == p0 + 1), pe2 = (pp0 == p0 + 2), pe3 = (pp0 == p0 + 3);
    #pragma unroll 8
    for (int n = 1; n < NC; ++n) {
        int pp = pk[n];
        float m = (pp >= 0) ? 1.0f : 0.0f;
        float4 v = sb[(size_t)n * (HW / 4) + g];
        float vx = v.x * m, vy = v.y * m, vz = v.z * m, vw = v.w * m;
        if (vx > bx) { bx = vx; ix = n; }
        if (vy > by) { by = vy; iy = n; }
        if (vz > bz) { bz = vz; iz = n; }
        if (vw > bw) { bw = vw; iw = n; }
        pe0 |= (pp == p0); pe1 |= (pp == p0 + 1); pe2 |= (pp == p0 + 2); pe3 |= (pp == p0 + 3);
    }
    if (pe0) { bx = 0.0f; ix = 0; }
    if (pe1) { by = 0.0f; iy = 0; }
    if (pe2) { bz = 0.0f; iz = 0; }
    if (pe3) { bw = 0.0f; iw = 0; }
    ((float4*)maxv)[(size_t)b * (HW / 4) + g] = make_float4(bx, by, bz, bw);
    ((int4*)clsidx)[(size_t)b * (HW / 4) + g] = make_int4(ix, iy, iz, iw);
}

// ---------------- radix-select top-128 + build map ----------------
__global__ __launch_bounds__(1024) void k_topk(const float* __restrict__ maxv,
                                               const int* __restrict__ clsidx,
                                               float* __restrict__ topkv,
                                               int* __restrict__ topki,
                                               int* __restrict__ topkc,
                                               unsigned char* __restrict__ map) {
    __shared__ unsigned int hist[2048];
    __shared__ unsigned int wtot[16];
    __shared__ unsigned int woff[16];
    __shared__ unsigned int s_pref;
    __shared__ int s_rank;
    __shared__ unsigned int s_bin;
    __shared__ unsigned int s_above;

    int b = blockIdx.x, t = threadIdx.x;
    int lane = t & 63, wid = t >> 6;

    // zero this batch's map (16 KB)
    {
        unsigned int* mz = (unsigned int*)(map + (size_t)b * HW);
        #pragma unroll
        for (int j = 0; j < 4; ++j) mz[j * 1024 + t] = 0u;
    }

    unsigned int key[16];
    const float4* mv4 = (const float4*)(maxv + (size_t)b * HW);
    #pragma unroll
    for (int j4 = 0; j4 < 4; ++j4) {
        float4 v = mv4[t * 4 + j4];
        key[j4 * 4 + 0] = __float_as_uint(v.x);
        key[j4 * 4 + 1] = __float_as_uint(v.y);
        key[j4 * 4 + 2] = __float_as_uint(v.z);
        key[j4 * 4 + 3] = __float_as_uint(v.w);
    }

    if (t == 0) { s_pref = 0u; s_rank = TOPK; }

    const int shifts[3] = {21, 10, 0};
    const int widths[3] = {11, 11, 10};

    for (int rnd = 0; rnd < 3; ++rnd) {
        int sh = shifts[rnd], w = widths[rnd];
        unsigned mask = (1u << w) - 1u;
        hist[t] = 0u; hist[t + 1024] = 0u;
        __syncthreads();
        unsigned pref = s_pref;
        int hiShift = sh + w;
        #pragma unroll
        for (int j = 0; j < 16; ++j) {
            unsigned k = key[j];
            bool ok = (rnd == 0) || ((k >> hiShift) == pref);
            if (ok) atomicAdd(&hist[(k >> sh) & mask], 1u);
        }
        __syncthreads();
        unsigned p = hist[2 * t] + hist[2 * t + 1];
        unsigned s = p;
        #pragma unroll
        for (int off = 1; off < 64; off <<= 1) {
            unsigned o = __shfl_down(s, off);
            if (lane + off < 64) s += o;
        }
        if (lane == 0) wtot[wid] = s;
        __syncthreads();
        if (wid == 0) {
            unsigned vv = (lane < 16) ? wtot[lane] : 0u;
            unsigned ss = vv;
            #pragma unroll
            for (int off = 1; off < 64; off <<= 1) {
                unsigned o = __shfl_down(ss, off);
                if (lane + off < 64) ss += o;
            }
            if (lane < 16) woff[lane] = ss - vv;
        }
        __syncthreads();
        unsigned S_t = s + woff[wid];
        unsigned S_next = S_t - p;
        int r = s_rank;
        if ((int)S_t >= r && (int)S_next < r) {
            unsigned hi = hist[2 * t + 1];
            if ((int)(S_next + hi) >= r) { s_bin = 2u * t + 1u; s_above = S_next; }
            else                         { s_bin = 2u * t;      s_above = S_next + hi; }
        }
        __syncthreads();
        if (t == 0) {
            s_pref = (s_pref << w) | s_bin;
            s_rank = s_rank - (int)s_above;
        }
        __syncthreads();
    }
    unsigned K = s_pref;
    int need_eq = s_rank;
    int cnt_gt = TOPK - need_eq;

    int cg = 0, ce = 0;
    #pragma unroll
    for (int j = 0; j < 16; ++j) { cg += (key[j] > K); ce += (key[j] == K); }
    unsigned v = ((unsigned)cg << 16) | (unsigned)ce;
    unsigned sc = v;
    #pragma unroll
    for (int off = 1; off < 64; off <<= 1) {
        unsigned o = __shfl_up(sc, off);
        if (lane >= off) sc += o;
    }
    if (lane == 63) wtot[wid] = sc;
    __syncthreads();
    if (wid == 0) {
        unsigned vv = (lane < 16) ? wtot[lane] : 0u;
        unsigned ss = vv;
        #pragma unroll
        for (int off = 1; off < 64; off <<= 1) {
            unsigned o = __shfl_up(ss, off);
            if (lane >= off) ss += o;
        }
        if (lane < 16) woff[lane] = ss - vv;
    }
    __syncthreads();
    unsigned ex = (sc - v) + woff[wid];
    int pg = (int)(ex >> 16);
    int pe = (int)(ex & 0xffffu);
    int lg = 0, le = 0;
    #pragma unroll
    for (int j = 0; j < 16; ++j) {
        unsigned k = key[j];
        int slot = -1;
        if (k > K) { slot = pg + lg; ++lg; }
        else if (k == K) { int er = pe + le; ++le; if (er < need_eq) slot = cnt_gt + er; }
        if (slot >= 0) {
            int idx = t * 16 + j;
            int cls = clsidx[(size_t)b * HW + idx];
            topkv[b * TOPK + slot] = __uint_as_float(k);
            topki[b * TOPK + slot] = idx;
            topkc[b * TOPK + slot] = cls;
            if (__uint_as_float(k) > 0.0f)
                map[(size_t)b * HW + idx] = (unsigned char)(cls + 1);  // byte store, race-free
        }
    }
}

// ---------------- gather & normalize feat at topk + peak positions ----------------
__global__ void k_gather(const float* __restrict__ feat, const int* __restrict__ peak_pos,
                         const int* __restrict__ topki, float* k_all, float* qv) {
    int bk = blockIdx.x;
    int b = bk / KALL, k = bk % KALL, c = threadIdx.x;
    int pos;
    if (k < TOPK) {
        pos = topki[b * TOPK + k];
    } else {
        int n = k - TOPK;
        int pp = peak_pos[b * NC + n];
        if (pp < 0) {
            k_all[((size_t)b * KALL + k) * C + c] = 0.0f;
            qv[((size_t)b * NC + n) * C + c] = 0.0f;
            return;
        }
        pos = pp;
    }
    float v = feat[((size_t)b * C + c) * HW + pos];
    float ss = v * v;
    #pragma unroll
    for (int off = 1; off < 64; off <<= 1) ss += __shfl_xor(ss, off);
    float qc = v / fmaxf(sqrtf(ss), EPSN);       // feat_n component
    if (k < TOPK) {
        k_all[((size_t)b * KALL + k) * C + c] = qc;
    } else {
        int n = k - TOPK;
        qv[((size_t)b * NC + n) * C + c] = qc;   // q (single-normalized)
        float qq = qc * qc;                      // k0 = normalize(q)
        #pragma unroll
        for (int off = 1; off < 64; off <<= 1) qq += __shfl_xor(qq, off);
        k_all[((size_t)b * KALL + k) * C + c] = qc / fmaxf(sqrtf(qq), EPSN);
    }
}

// ---------------- contrastive loss per (b,n) — fence-free ----------------
__global__ __launch_bounds__(256) void k_loss(const float* __restrict__ k_all,
                                              const float* __restrict__ qv,
                                              const int* __restrict__ peak_pos,
                                              const float* __restrict__ topkv,
                                              const int* __restrict__ topkc,
                                              float* __restrict__ loss_bn) {
    __shared__ float qs[C];
    __shared__ float r1[256];
    __shared__ float r2[256];
    __shared__ float s_simsum, s_num;
    int bn = blockIdx.x;
    int b = bn / NC, n = bn % NC, t = threadIdx.x;
    if (peak_pos[bn] < 0) { if (t == 0) loss_bn[bn] = 0.0f; return; }
    if (t < C) qs[t] = qv[(size_t)bn * C + t];
    __syncthreads();
    float sim = 0.0f, kam = 0.0f, km = 0.0f;
    if (t < KALL) {
        const float* kr = k_all + ((size_t)b * KALL + t) * C;
        float dot = 0.0f;
        for (int c2 = 0; c2 < C; ++c2) dot += qs[c2] * kr[c2];
        sim = expf(dot / TAU);
        if (t < TOPK) {
            float posm = (topkv[b * TOPK + t] > 0.0f) ? 1.0f : 0.0f;
            kam = posm;
            km = (topkc[b * TOPK + t] == n) ? posm : 0.0f;
        } else {
            int j = t - TOPK;
            kam = (peak_pos[b * NC + j] >= 0) ? 1.0f : 0.0f;
            km = (j == n) ? 1.0f : 0.0f;
        }
    }
    r1[t] = sim * kam;
    r2[t] = km;
    __syncthreads();
    for (int s = 128; s > 0; s >>= 1) {
        if (t < s) { r1[t] += r1[t + s]; r2[t] += r2[t + s]; }
        __syncthreads();
    }
    if (t == 0) {
        float ss = r1[0];
        s_simsum = (ss == 0.0f) ? 1.0f : ss;
        s_num = (r2[0] == 0.0f) ? 1.0f : r2[0];
    }
    __syncthreads();
    r1[t] = (km > 0.0f) ? logf(sim / s_simsum) : 0.0f;
    __syncthreads();
    for (int s = 128; s > 0; s >>= 1) {
        if (t < s) r1[t] += r1[t + s];
        __syncthreads();
    }
    if (t == 0) loss_bn[bn] = r1[0] / s_num;
}

// ---------------- pure streaming writer (+ lone final-reduce block) ----------------
// out[1+linear] = (map[b][pos] == n+1) ? 0.9 : 0, fully coalesced, no fences.
__global__ __launch_bounds__(256) void k_write_final(const unsigned char* __restrict__ map,
                                                     const float* __restrict__ loss_bn,
                                                     const int* __restrict__ peak_pos,
                                                     float* __restrict__ out) {
    int t = threadIdx.x;
    if (blockIdx.x < WBLK) {
        int base = blockIdx.x * 8192 + t;            // pseudo element, k=0
        #pragma unroll
        for (int k = 0; k < 32; ++k) {
            int linear = base + k * 256;             // [0, 20971520)
            int hi = linear >> 14;                   // (b*NC + n)
            int bb = hi / NC;                        // magic-div by 80
            int n1 = hi - bb * NC + 1;               // n+1
            int pos = linear & (HW - 1);
            unsigned char mp = map[(bb << 14) + pos];
            float v = (mp == (unsigned char)n1) ? 0.9f : 0.0f;
            __builtin_nontemporal_store(v, &out[1 + linear]);
        }
        return;
    }
    // ---- final loss reduction (single block; loss_bn from previous kernel) ----
    __shared__ float r1[256];
    __shared__ float r2[256];
    float s = 0.0f, cnt = 0.0f;
    for (int i = t; i < BS * NC; i += 256) {
        s += loss_bn[i];
        cnt += (peak_pos[i] >= 0) ? 1.0f : 0.0f;
    }
    r1[t] = s; r2[t] = cnt;
    __syncthreads();
    for (int st = 128; st > 0; st >>= 1) {
        if (t < st) { r1[t] += r1[t + st]; r2[t] += r2[t + st]; }
        __syncthreads();
    }
    if (t == 0) out[0] = -(r1[0] / r2[0]);
}

extern "C" void kernel_launch(void* const* d_in, const int* in_sizes, int n_in,
                              void* d_out, int out_size, void* d_ws, size_t ws_size,
                              hipStream_t stream) {
    const float* feat  = (const float*)d_in[0];
    const float* score = (const float*)d_in[1];
    const float* hm    = (const float*)d_in[2];
    float* out = (float*)d_out;

    char* ws = (char*)d_ws;
    size_t off = 0;
    auto alloc = [&](size_t bytes) -> void* {
        void* p = ws + off;
        off += (bytes + 255) & ~(size_t)255;
        return p;
    };
    int*   peak_pos = (int*)  alloc((size_t)BS * NC * 4);
    float* maxv     = (float*)alloc((size_t)BS * HW * 4);
    int*   clsidx   = (int*)  alloc((size_t)BS * HW * 4);
    float* topkv    = (float*)alloc((size_t)BS * TOPK * 4);
    int*   topki    = (int*)  alloc((size_t)BS * TOPK * 4);
    int*   topkc    = (int*)  alloc((size_t)BS * TOPK * 4);
    float* k_all    = (float*)alloc((size_t)BS * KALL * C * 4);
    float* qv       = (float*)alloc((size_t)BS * NC * C * 4);
    float* loss_bn  = (float*)alloc((size_t)BS * NC * 4);
    unsigned char* map = (unsigned char*)alloc((size_t)BS * HW);

    k_peak<<<BS * NC, 1024, 0, stream>>>(hm, peak_pos);
    dim3 gmax(HW / 4 / 256, BS);
    k_max<<<gmax, 256, 0, stream>>>(score, peak_pos, maxv, clsidx);
    k_topk<<<BS, 1024, 0, stream>>>(maxv, clsidx, topkv, topki, topkc, map);
    k_gather<<<BS * KALL, 64, 0, stream>>>(feat, peak_pos, topki, k_all, qv);
    k_loss<<<BS * NC, 256, 0, stream>>>(k_all, qv, peak_pos, topkv, topkc, loss_bn);
    k_write_final<<<WBLK + 1, 256, 0, stream>>>(map, loss_bn, peak_pos, out);
}

// Round 8
// 98.858 us; speedup vs baseline: 2.3584x; 1.0300x over previous
//
#include <hip/hip_runtime.h>
#include <math.h>

#define BS 16
#define C 64
#define H 128
#define W 128
#define HW (H*W)
#define NC 80
#define TOPK 128
#define KALL (TOPK+NC)
#define TAU 0.07f
#define EPSN 1e-12f
#define OUT_N 20971521          // 1 + BS*NC*HW
#define NCHW (NC*HW)            // 1310720
#define WBLK 2560               // writer blocks: 256 thr x 8 float4 = 32 KB/block
#define GBLK (BS*KALL/4)       // 832 gather blocks (4 waves each)

// ---------------- find hm==1.0 peak per (b,n); -1 if absent ----------------
__global__ __launch_bounds__(1024) void k_peak(const float* __restrict__ hm,
                                               int* __restrict__ peak_pos) {
    __shared__ int wmax[16];
    int bn = blockIdx.x, t = threadIdx.x;
    int lane = t & 63, wid = t >> 6;
    const float4* p = (const float4*)(hm + (size_t)bn * HW);
    int found = -1;
    #pragma unroll
    for (int j = 0; j < 4; ++j) {
        int gi = j * 1024 + t;
        float4 v = p[gi];
        int base = gi * 4;
        if (v.x == 1.0f) found = base;
        if (v.y == 1.0f) found = base + 1;
        if (v.z == 1.0f) found = base + 2;
        if (v.w == 1.0f) found = base + 3;
    }
    #pragma unroll
    for (int off = 1; off < 64; off <<= 1) found = max(found, __shfl_xor(found, off));
    if (lane == 0) wmax[wid] = found;
    __syncthreads();
    if (t == 0) {
        int m = wmax[0];
        #pragma unroll
        for (int i = 1; i < 16; ++i) m = max(m, wmax[i]);
        peak_pos[bn] = m;
    }
}

// ---------------- per-pixel masked max/argmax over classes (4 px/thread) ----------------
__global__ void k_max(const float* __restrict__ score, const int* __restrict__ peak_pos,
                      float* __restrict__ maxv, int* __restrict__ clsidx) {
    __shared__ int pk[NC];
    int b = blockIdx.y;
    int g = blockIdx.x * blockDim.x + threadIdx.x;   // float4 group 0..4095
    if (threadIdx.x < NC) pk[threadIdx.x] = peak_pos[b * NC + threadIdx.x];
    __syncthreads();
    const float4* sb = (const float4*)(score + (size_t)b * NC * HW);
    int p0 = g * 4;
    int pp0 = pk[0];
    float m0 = (pp0 >= 0) ? 1.0f : 0.0f;
    float4 v0 = sb[g];
    float bx = v0.x * m0, by = v0.y * m0, bz = v0.z * m0, bw = v0.w * m0;
    int ix = 0, iy = 0, iz = 0, iw = 0;
    bool pe0 = (pp0 == p0), pe1 = (pp0 == p0 + 1), pe2 = (pp0 == p0 + 2), pe3 = (pp0 == p0 + 3);
    #pragma unroll 8
    for (int n = 1; n < NC; ++n) {
        int pp = pk[n];
        float m = (pp >= 0) ? 1.0f : 0.0f;
        float4 v = sb[(size_t)n * (HW / 4) + g];
        float vx = v.x * m, vy = v.y * m, vz = v.z * m, vw = v.w * m;
        if (vx > bx) { bx = vx; ix = n; }
        if (vy > by) { by = vy; iy = n; }
        if (vz > bz) { bz = vz; iz = n; }
        if (vw > bw) { bw = vw; iw = n; }
        pe0 |= (pp == p0); pe1 |= (pp == p0 + 1); pe2 |= (pp == p0 + 2); pe3 |= (pp == p0 + 3);
    }
    if (pe0) { bx = 0.0f; ix = 0; }
    if (pe1) { by = 0.0f; iy = 0; }
    if (pe2) { bz = 0.0f; iz = 0; }
    if (pe3) { bw = 0.0f; iw = 0; }
    ((float4*)maxv)[(size_t)b * (HW / 4) + g] = make_float4(bx, by, bz, bw);
    ((int4*)clsidx)[(size_t)b * (HW / 4) + g] = make_int4(ix, iy, iz, iw);
}

// ---------------- radix-select top-128 + build map ----------------
__global__ __launch_bounds__(1024) void k_topk(const float* __restrict__ maxv,
                                               const int* __restrict__ clsidx,
                                               float* __restrict__ topkv,
                                               int* __restrict__ topki,
                                               int* __restrict__ topkc,
                                               unsigned char* __restrict__ map) {
    __shared__ unsigned int hist[2048];
    __shared__ unsigned int wtot[16];
    __shared__ unsigned int woff[16];
    __shared__ unsigned int s_pref;
    __shared__ int s_rank;
    __shared__ unsigned int s_bin;
    __shared__ unsigned int s_above;

    int b = blockIdx.x, t = threadIdx.x;
    int lane = t & 63, wid = t >> 6;

    // zero this batch's map (16 KB)
    {
        unsigned int* mz = (unsigned int*)(map + (size_t)b * HW);
        #pragma unroll
        for (int j = 0; j < 4; ++j) mz[j * 1024 + t] = 0u;
    }

    unsigned int key[16];
    const float4* mv4 = (const float4*)(maxv + (size_t)b * HW);
    #pragma unroll
    for (int j4 = 0; j4 < 4; ++j4) {
        float4 v = mv4[t * 4 + j4];
        key[j4 * 4 + 0] = __float_as_uint(v.x);
        key[j4 * 4 + 1] = __float_as_uint(v.y);
        key[j4 * 4 + 2] = __float_as_uint(v.z);
        key[j4 * 4 + 3] = __float_as_uint(v.w);
    }

    if (t == 0) { s_pref = 0u; s_rank = TOPK; }

    const int shifts[3] = {21, 10, 0};
    const int widths[3] = {11, 11, 10};

    for (int rnd = 0; rnd < 3; ++rnd) {
        int sh = shifts[rnd], w = widths[rnd];
        unsigned mask = (1u << w) - 1u;
        hist[t] = 0u; hist[t + 1024] = 0u;
        __syncthreads();
        unsigned pref = s_pref;
        int hiShift = sh + w;
        #pragma unroll
        for (int j = 0; j < 16; ++j) {
            unsigned k = key[j];
            bool ok = (rnd == 0) || ((k >> hiShift) == pref);
            if (ok) atomicAdd(&hist[(k >> sh) & mask], 1u);
        }
        __syncthreads();
        unsigned p = hist[2 * t] + hist[2 * t + 1];
        unsigned s = p;
        #pragma unroll
        for (int off = 1; off < 64; off <<= 1) {
            unsigned o = __shfl_down(s, off);
            if (lane + off < 64) s += o;
        }
        if (lane == 0) wtot[wid] = s;
        __syncthreads();
        if (wid == 0) {
            unsigned vv = (lane < 16) ? wtot[lane] : 0u;
            unsigned ss = vv;
            #pragma unroll
            for (int off = 1; off < 64; off <<= 1) {
                unsigned o = __shfl_down(ss, off);
                if (lane + off < 64) ss += o;
            }
            if (lane < 16) woff[lane] = ss - vv;
        }
        __syncthreads();
        unsigned S_t = s + woff[wid];
        unsigned S_next = S_t - p;
        int r = s_rank;
        if ((int)S_t >= r && (int)S_next < r) {
            unsigned hi = hist[2 * t + 1];
            if ((int)(S_next + hi) >= r) { s_bin = 2u * t + 1u; s_above = S_next; }
            else                         { s_bin = 2u * t;      s_above = S_next + hi; }
        }
        __syncthreads();
        if (t == 0) {
            s_pref = (s_pref << w) | s_bin;
            s_rank = s_rank - (int)s_above;
        }
        __syncthreads();
    }
    unsigned K = s_pref;
    int need_eq = s_rank;
    int cnt_gt = TOPK - need_eq;

    int cg = 0, ce = 0;
    #pragma unroll
    for (int j = 0; j < 16; ++j) { cg += (key[j] > K); ce += (key[j] == K); }
    unsigned v = ((unsigned)cg << 16) | (unsigned)ce;
    unsigned sc = v;
    #pragma unroll
    for (int off = 1; off < 64; off <<= 1) {
        unsigned o = __shfl_up(sc, off);
        if (lane >= off) sc += o;
    }
    if (lane == 63) wtot[wid] = sc;
    __syncthreads();
    if (wid == 0) {
        unsigned vv = (lane < 16) ? wtot[lane] : 0u;
        unsigned ss = vv;
        #pragma unroll
        for (int off = 1; off < 64; off <<= 1) {
            unsigned o = __shfl_up(ss, off);
            if (lane >= off) ss += o;
        }
        if (lane < 16) woff[lane] = ss - vv;
    }
    __syncthreads();
    unsigned ex = (sc - v) + woff[wid];
    int pg = (int)(ex >> 16);
    int pe = (int)(ex & 0xffffu);
    int lg = 0, le = 0;
    #pragma unroll
    for (int j = 0; j < 16; ++j) {
        unsigned k = key[j];
        int slot = -1;
        if (k > K) { slot = pg + lg; ++lg; }
        else if (k == K) { int er = pe + le; ++le; if (er < need_eq) slot = cnt_gt + er; }
        if (slot >= 0) {
            int idx = t * 16 + j;
            int cls = clsidx[(size_t)b * HW + idx];
            topkv[b * TOPK + slot] = __uint_as_float(k);
            topki[b * TOPK + slot] = idx;
            topkc[b * TOPK + slot] = cls;
            if (__uint_as_float(k) > 0.0f)
                map[(size_t)b * HW + idx] = (unsigned char)(cls + 1);  // byte store, race-free
        }
    }
}

// ---------------- fused: pseudo_hm streaming write + feat gather/normalize ----------------
// Writer blocks [0, WBLK): cached float4 stores, out[4g..4g+3] <- pseudo(4g-1..4g+2).
// Gather blocks [WBLK, WBLK+GBLK): 4 waves/block, one (b,k) per wave.
__global__ __launch_bounds__(256) void k_write_gather(const unsigned char* __restrict__ map,
                                                      const float* __restrict__ feat,
                                                      const int* __restrict__ peak_pos,
                                                      const int* __restrict__ topki,
                                                      float* __restrict__ k_all,
                                                      float* __restrict__ qv,
                                                      float* __restrict__ out) {
    int t = threadIdx.x;
    if (blockIdx.x < WBLK) {
        float4* o4 = (float4*)out;
        #pragma unroll
        for (int j = 0; j < 8; ++j) {
            int g = blockIdx.x * 2048 + j * 256 + t;     // [0, 5242880)
            if (g == 0) continue;                        // handled below
            float r[4];
            #pragma unroll
            for (int e = 0; e < 4; ++e) {
                int linear = 4 * g - 1 + e;              // pseudo element index
                int hi = linear >> 14;                   // b*NC + n
                int bb = hi / NC;                        // magic-div
                int n1 = hi - bb * NC + 1;
                int pos = linear & (HW - 1);
                unsigned char mp = map[(bb << 14) + pos];
                r[e] = (mp == (unsigned char)n1) ? 0.9f : 0.0f;
            }
            o4[g] = make_float4(r[0], r[1], r[2], r[3]);
        }
        if (blockIdx.x == 0 && t == 0) {
            // scalar edges: out[1..3] (linear 0..2) and out[OUT_N-1] (linear OUT_N-2)
            #pragma unroll
            for (int e = 0; e < 3; ++e) {
                int linear = e;
                unsigned char mp = map[linear & (HW - 1)];   // b=0,n=0
                out[1 + linear] = (mp == (unsigned char)1) ? 0.9f : 0.0f;
            }
            int linear = OUT_N - 2;
            int hi = linear >> 14;
            int bb = hi / NC;
            int n1 = hi - bb * NC + 1;
            int pos = linear & (HW - 1);
            unsigned char mp = map[(bb << 14) + pos];
            out[OUT_N - 1] = (mp == (unsigned char)n1) ? 0.9f : 0.0f;
        }
        return;
    }
    // ---- gather: one (b,k) per wave ----
    int wid = t >> 6, lane = t & 63;
    int bk = (blockIdx.x - WBLK) * 4 + wid;              // [0, BS*KALL)
    int b = bk / KALL, k = bk % KALL, c = lane;
    int pos;
    if (k < TOPK) {
        pos = topki[b * TOPK + k];
    } else {
        int n = k - TOPK;
        int pp = peak_pos[b * NC + n];
        if (pp < 0) {
            k_all[((size_t)b * KALL + k) * C + c] = 0.0f;
            qv[((size_t)b * NC + n) * C + c] = 0.0f;
            return;
        }
        pos = pp;
    }
    float v = feat[((size_t)b * C + c) * HW + pos];
    float ss = v * v;
    #pragma unroll
    for (int off = 1; off < 64; off <<= 1) ss += __shfl_xor(ss, off);
    float qc = v / fmaxf(sqrtf(ss), EPSN);       // feat_n component
    if (k < TOPK) {
        k_all[((size_t)b * KALL + k) * C + c] = qc;
    } else {
        int n = k - TOPK;
        qv[((size_t)b * NC + n) * C + c] = qc;   // q (single-normalized)
        float qq = qc * qc;                      // k0 = normalize(q)
        #pragma unroll
        for (int off = 1; off < 64; off <<= 1) qq += __shfl_xor(qq, off);
        k_all[((size_t)b * KALL + k) * C + c] = qc / fmaxf(sqrtf(qq), EPSN);
    }
}

// ---------------- contrastive loss per (b,n) — fence-free ----------------
__global__ __launch_bounds__(256) void k_loss(const float* __restrict__ k_all,
                                              const float* __restrict__ qv,
                                              const int* __restrict__ peak_pos,
                                              const float* __restrict__ topkv,
                                              const int* __restrict__ topkc,
                                              float* __restrict__ loss_bn) {
    __shared__ float qs[C];
    __shared__ float r1[256];
    __shared__ float r2[256];
    __shared__ float s_simsum, s_num;
    int bn = blockIdx.x;
    int b = bn / NC, n = bn % NC, t = threadIdx.x;
    if (peak_pos[bn] < 0) { if (t == 0) loss_bn[bn] = 0.0f; return; }
    if (t < C) qs[t] = qv[(size_t)bn * C + t];
    __syncthreads();
    float sim = 0.0f, kam = 0.0f, km = 0.0f;
    if (t < KALL) {
        const float* kr = k_all + ((size_t)b * KALL + t) * C;
        float dot = 0.0f;
        for (int c2 = 0; c2 < C; ++c2) dot += qs[c2] * kr[c2];
        sim = expf(dot / TAU);
        if (t < TOPK) {
            float posm = (topkv[b * TOPK + t] > 0.0f) ? 1.0f : 0.0f;
            kam = posm;
            km = (topkc[b * TOPK + t] == n) ? posm : 0.0f;
        } else {
            int j = t - TOPK;
            kam = (peak_pos[b * NC + j] >= 0) ? 1.0f : 0.0f;
            km = (j == n) ? 1.0f : 0.0f;
        }
    }
    r1[t] = sim * kam;
    r2[t] = km;
    __syncthreads();
    for (int s = 128; s > 0; s >>= 1) {
        if (t < s) { r1[t] += r1[t + s]; r2[t] += r2[t + s]; }
        __syncthreads();
    }
    if (t == 0) {
        float ss = r1[0];
        s_simsum = (ss == 0.0f) ? 1.0f : ss;
        s_num = (r2[0] == 0.0f) ? 1.0f : r2[0];
    }
    __syncthreads();
    r1[t] = (km > 0.0f) ? logf(sim / s_simsum) : 0.0f;
    __syncthreads();
    for (int s = 128; s > 0; s >>= 1) {
        if (t < s) r1[t] += r1[t + s];
        __syncthreads();
    }
    if (t == 0) loss_bn[bn] = r1[0] / s_num;
}

// ---------------- final deterministic loss reduction ----------------
__global__ __launch_bounds__(256) void k_final(const float* __restrict__ loss_bn,
                                               const int* __restrict__ peak_pos,
                                               float* __restrict__ out) {
    __shared__ float r1[256];
    __shared__ float r2[256];
    int t = threadIdx.x;
    float s = 0.0f, cnt = 0.0f;
    for (int i = t; i < BS * NC; i += 256) {
        s += loss_bn[i];
        cnt += (peak_pos[i] >= 0) ? 1.0f : 0.0f;
    }
    r1[t] = s; r2[t] = cnt;
    __syncthreads();
    for (int st = 128; st > 0; st >>= 1) {
        if (t < st) { r1[t] += r1[t + st]; r2[t] += r2[t + st]; }
        __syncthreads();
    }
    if (t == 0) out[0] = -(r1[0] / r2[0]);
}

extern "C" void kernel_launch(void* const* d_in, const int* in_sizes, int n_in,
                              void* d_out, int out_size, void* d_ws, size_t ws_size,
                              hipStream_t stream) {
    const float* feat  = (const float*)d_in[0];
    const float* score = (const float*)d_in[1];
    const float* hm    = (const float*)d_in[2];
    float* out = (float*)d_out;

    char* ws = (char*)d_ws;
    size_t off = 0;
    auto alloc = [&](size_t bytes) -> void* {
        void* p = ws + off;
        off += (bytes + 255) & ~(size_t)255;
        return p;
    };
    int*   peak_pos = (int*)  alloc((size_t)BS * NC * 4);
    float* maxv     = (float*)alloc((size_t)BS * HW * 4);
    int*   clsidx   = (int*)  alloc((size_t)BS * HW * 4);
    float* topkv    = (float*)alloc((size_t)BS * TOPK * 4);
    int*   topki    = (int*)  alloc((size_t)BS * TOPK * 4);
    int*   topkc    = (int*)  alloc((size_t)BS * TOPK * 4);
    float* k_all    = (float*)alloc((size_t)BS * KALL * C * 4);
    float* qv       = (float*)alloc((size_t)BS * NC * C * 4);
    float* loss_bn  = (float*)alloc((size_t)BS * NC * 4);
    unsigned char* map = (unsigned char*)alloc((size_t)BS * HW);

    k_peak<<<BS * NC, 1024, 0, stream>>>(hm, peak_pos);
    dim3 gmax(HW / 4 / 256, BS);
    k_max<<<gmax, 256, 0, stream>>>(score, peak_pos, maxv, clsidx);
    k_topk<<<BS, 1024, 0, stream>>>(maxv, clsidx, topkv, topki, topkc, map);
    k_write_gather<<<WBLK + GBLK, 256, 0, stream>>>(map, feat, peak_pos, topki,
                                                    k_all, qv, out);
    k_loss<<<BS * NC, 256, 0, stream>>>(k_all, qv, peak_pos, topkv, topkc, loss_bn);
    k_final<<<1, 256, 0, stream>>>(loss_bn, peak_pos, out);
}